// Round 2
// baseline (17593.790 us; speedup 1.0000x reference)
//
#include <hip/hip_runtime.h>

// SimpleLSTM: V=95, H=2048, B=256, SQ=162, 15 think + 29 answer steps.
// Round 1: fused gate epilogue (gate-interleaved W layout), 128x64 tile,
// double-buffered BK=32 pipeline, h ping-pong buffers.

#define Hdim 2048
#define G4H  8192
#define Bsz  256
#define Vsz  95
#define SQL  162
#define TSTEPS 15
#define ASTEPS 29

typedef unsigned short u16;
typedef __attribute__((ext_vector_type(8))) short bf16x8;
typedef __attribute__((ext_vector_type(4))) float f32x4;

__device__ __forceinline__ u16 f2bf(float x) {
  unsigned u = __float_as_uint(x);
  return (u16)((u + 0x7fffu + ((u >> 16) & 1u)) >> 16);
}
__device__ __forceinline__ float bf2f(u16 v) {
  return __uint_as_float(((unsigned)v) << 16);
}
__device__ __forceinline__ void splitbf(float x, u16& hi, u16& lo) {
  hi = f2bf(x);
  lo = f2bf(x - bf2f(hi));
}
__device__ __forceinline__ float sigm(float x) { return 1.0f / (1.0f + expf(-x)); }

__device__ __forceinline__ void gll16(const u16* g, u16* l) {
  __builtin_amdgcn_global_load_lds(
      (const __attribute__((address_space(1))) void*)g,
      (__attribute__((address_space(3))) void*)l, 16, 0, 0);
}

// ---------------- init: gate-interleaved split of W_hh ----------------
// n = 4*hh + gate ; source row r = gate*2048 + hh = (n&3)*2048 + (n>>2)
__global__ void k_split2(const float* __restrict__ w, u16* __restrict__ whi,
                         u16* __restrict__ wlo) {
  for (long i = blockIdx.x * blockDim.x + threadIdx.x; i < (long)G4H * Hdim;
       i += (long)gridDim.x * blockDim.x) {
    int n = (int)(i >> 11), k = (int)(i & 2047);
    long r = (long)((n & 3) * Hdim + (n >> 2));
    u16 a, b;
    splitbf(w[r * Hdim + k], a, b);
    whi[i] = a;
    wlo[i] = b;
  }
}

__global__ void k_prep(const float* __restrict__ W_ih, const float* __restrict__ b_ih,
                       const float* __restrict__ b_hh, float* __restrict__ wihT2,
                       float* __restrict__ bias2, float* __restrict__ h,
                       float* __restrict__ c, u16* __restrict__ h_hi,
                       u16* __restrict__ h_lo) {
  int i = blockIdx.x * 256 + threadIdx.x;
  if (i < Vsz * G4H) {
    int v = i / G4H, n = i % G4H;
    int r = (n & 3) * Hdim + (n >> 2);
    wihT2[i] = W_ih[(long)r * Vsz + v];
  }
  if (i < G4H) {
    int r = (i & 3) * Hdim + (i >> 2);
    bias2[i] = b_ih[r] + b_hh[r];
  }
  if (i < Bsz * Hdim) {
    h[i] = 0.f;
    c[i] = 0.f;
    h_hi[i] = 0;
    h_lo[i] = 0;
  }
}

// ---------------- fused step: g = h@W_hh.T (+input) -> gates -> h,c ----------
// A = h_in (256x2048 bf16 hi/lo), B = whh2 (8192x2048 bf16 hi/lo, interleaved).
// Tile BM=128 BN=64 BK=32, grid (2,128), 4 waves (2Mx2N, wave 64x32).
// LDS: 2 x 24KB double buffer [Ah 8K | Al 8K | Bh 4K | Bl 4K], instr-ordered.
__global__ __launch_bounds__(256) void k_step(
    const u16* __restrict__ a_hi, const u16* __restrict__ a_lo,
    const u16* __restrict__ b_hi, const u16* __restrict__ b_lo,
    const float* __restrict__ bias2, const float* __restrict__ wihT2,
    const float* __restrict__ ic, const int* __restrict__ x, int tstep,
    int xstride, int mode, float* __restrict__ c, float* __restrict__ hf,
    u16* __restrict__ o_hi, u16* __restrict__ o_lo) {
  __shared__ __align__(16) u16 SM[24576];  // 48 KB

  const int tid = threadIdx.x;
  const int wave = tid >> 6, lane = tid & 63;
  const int row0 = blockIdx.x * 128, col0 = blockIdx.y * 64;
  const int wr = wave >> 1, wc = wave & 1;
  const int lr = lane & 15, lc = lane >> 4;

  // --- staging: 6 global_load_lds per wave per K-round, instr id cc=wave*6+j
  const u16* gsrc[6];
  u16* ldst[6];
#pragma unroll
  for (int j = 0; j < 6; ++j) {
    int cc = wave * 6 + j;
    const u16* base;
    long rg;
    if (cc < 8)       { base = a_hi; rg = row0 + cc * 16; }
    else if (cc < 16) { base = a_lo; rg = row0 + (cc - 8) * 16; }
    else if (cc < 20) { base = b_hi; rg = col0 + (cc - 16) * 16; }
    else              { base = b_lo; rg = col0 + (cc - 20) * 16; }
    // per-lane: row += lane>>2 ; source k pre-swizzled (G21 both-sides XOR)
    gsrc[j] = base + (rg + (lane >> 2)) * (long)Hdim +
              (((lane & 3) ^ ((lane >> 2) & 3)) * 8);
    ldst[j] = SM + cc * 512;  // 1KB per instr, linear LDS dest
  }

  // --- read offsets (bytes within buffer), swizzled k-slot
  const int sl = (lc ^ (lr & 3)) * 16;
  int aoff[4], boff[2];
#pragma unroll
  for (int mf = 0; mf < 4; ++mf) aoff[mf] = (wr * 64 + mf * 16 + lr) * 64 + sl;
#pragma unroll
  for (int nf = 0; nf < 2; ++nf) boff[nf] = 16384 + (wc * 32 + nf * 16 + lr) * 64 + sl;

  f32x4 acc[4][2] = {};

  // prologue: stage kb=0 into buffer 0
#pragma unroll
  for (int j = 0; j < 6; ++j) gll16(gsrc[j], ldst[j]);
  __syncthreads();

  const char* smb = (const char*)SM;
  for (int kb = 0; kb < 64; ++kb) {
    const int buf = (kb & 1) * 24576;
    if (kb < 63) {
      const int nb = ((kb + 1) & 1) * 12288;  // u16 units
#pragma unroll
      for (int j = 0; j < 6; ++j) gll16(gsrc[j] + (kb + 1) * 32, ldst[j] + nb);
    }
    bf16x8 ah[4], al[4], bh[2], bl[2];
#pragma unroll
    for (int mf = 0; mf < 4; ++mf) {
      ah[mf] = *(const bf16x8*)(smb + buf + aoff[mf]);
      al[mf] = *(const bf16x8*)(smb + buf + 8192 + aoff[mf]);
    }
#pragma unroll
    for (int nf = 0; nf < 2; ++nf) {
      bh[nf] = *(const bf16x8*)(smb + buf + boff[nf]);
      bl[nf] = *(const bf16x8*)(smb + buf + 4096 + boff[nf]);
    }
    // term 1: ah*bh
#pragma unroll
    for (int mf = 0; mf < 4; ++mf)
#pragma unroll
      for (int nf = 0; nf < 2; ++nf)
        acc[mf][nf] = __builtin_amdgcn_mfma_f32_16x16x32_bf16(ah[mf], bh[nf], acc[mf][nf], 0, 0, 0);
    // term 2: ah*bl
#pragma unroll
    for (int mf = 0; mf < 4; ++mf)
#pragma unroll
      for (int nf = 0; nf < 2; ++nf)
        acc[mf][nf] = __builtin_amdgcn_mfma_f32_16x16x32_bf16(ah[mf], bl[nf], acc[mf][nf], 0, 0, 0);
    // term 3: al*bh
#pragma unroll
    for (int mf = 0; mf < 4; ++mf)
#pragma unroll
      for (int nf = 0; nf < 2; ++nf)
        acc[mf][nf] = __builtin_amdgcn_mfma_f32_16x16x32_bf16(al[mf], bh[nf], acc[mf][nf], 0, 0, 0);
    __syncthreads();
  }

  // --- epilogue: stage g-tile in LDS (padded stride 68), then fused gates
  float* gt = (float*)SM;
#pragma unroll
  for (int mf = 0; mf < 4; ++mf)
#pragma unroll
    for (int nf = 0; nf < 2; ++nf) {
      int col = wc * 32 + nf * 16 + lr;
#pragma unroll
      for (int i = 0; i < 4; ++i) {
        int row = wr * 64 + mf * 16 + lc * 4 + i;
        gt[row * 68 + col] = acc[mf][nf][i];
      }
    }
  __syncthreads();

  const int h16 = tid & 15;       // hh local (16 per block)
  const int bl16 = tid >> 4;      // 0..15
  const int hh_g = (col0 >> 2) + h16;
  const float bi = bias2[col0 + 4 * h16 + 0];
  const float bf_ = bias2[col0 + 4 * h16 + 1];
  const float bg_ = bias2[col0 + 4 * h16 + 2];
  const float bo = bias2[col0 + 4 * h16 + 3];
#pragma unroll
  for (int p = 0; p < 8; ++p) {
    int brow = p * 16 + bl16;
    int bg = row0 + brow;
    const float* gr = &gt[brow * 68 + 4 * h16];
    float xi = gr[0] + bi, xf = gr[1] + bf_, xg = gr[2] + bg_, xo = gr[3] + bo;
    if (mode == 1) {
      int tok = x[(bg * SQL + tstep) * xstride];
      const float* wv = wihT2 + (long)tok * G4H + col0 + 4 * h16;
      xi += wv[0]; xf += wv[1]; xg += wv[2]; xo += wv[3];
    } else if (mode == 2) {
      const float* iv = ic + (long)bg * G4H + col0 + 4 * h16;
      xi += iv[0]; xf += iv[1]; xg += iv[2]; xo += iv[3];
    }
    long ci = (long)bg * Hdim + hh_g;
    float cn = sigm(xf) * c[ci] + sigm(xi) * tanhf(xg);
    float hn = sigm(xo) * tanhf(cn);
    c[ci] = cn;
    hf[ci] = hn;
    u16 h_, l_;
    splitbf(hn, h_, l_);
    o_hi[ci] = h_;
    o_lo[ci] = l_;
  }
}

// ---------------- logits = src @ W_proj.T (fp32) ----------------
__global__ __launch_bounds__(256) void k_logits(const float* __restrict__ src,
                                                const float* __restrict__ Wp,
                                                float* __restrict__ lg,
                                                float* __restrict__ outp) {
  __shared__ float hl[Hdim];
  int b = blockIdx.x, tid = threadIdx.x;
  for (int k = tid; k < Hdim; k += 256) hl[k] = src[(long)b * Hdim + k];
  __syncthreads();
  int wv = tid >> 6, ln = tid & 63;
  for (int v = wv; v < Vsz; v += 4) {
    const float* wrow = Wp + (long)v * Hdim;
    float s = 0.f;
    for (int k = ln; k < Hdim; k += 64) s += wrow[k] * hl[k];
#pragma unroll
    for (int off = 32; off; off >>= 1) s += __shfl_down(s, off);
    if (ln == 0) {
      lg[b * Vsz + v] = s;
      outp[b * Vsz + v] = s;
    }
  }
}

// ---------------- ic = logits @ W_ih.T (K=95), gate-interleaved out --------
__global__ __launch_bounds__(256) void k_ic(const float* __restrict__ lg,
                                            const float* __restrict__ wihT2,
                                            float* __restrict__ ic) {
  __shared__ float ll[8 * Vsz];
  int jg = blockIdx.x, bgp = blockIdx.y, tid = threadIdx.x;
  int j = jg * 256 + tid;
  for (int i = tid; i < 8 * Vsz; i += 256) ll[i] = lg[bgp * 8 * Vsz + i];
  __syncthreads();
  float a[8] = {0, 0, 0, 0, 0, 0, 0, 0};
  for (int v = 0; v < Vsz; ++v) {
    float w = wihT2[(long)v * G4H + j];
#pragma unroll
    for (int bb = 0; bb < 8; ++bb) a[bb] += ll[bb * Vsz + v] * w;
  }
#pragma unroll
  for (int bb = 0; bb < 8; ++bb) ic[(long)(bgp * 8 + bb) * G4H + j] = a[bb];
}

// ---------------- host ----------------
extern "C" void kernel_launch(void* const* d_in, const int* in_sizes, int n_in,
                              void* d_out, int out_size, void* d_ws, size_t ws_size,
                              hipStream_t stream) {
  const int* x = (const int*)d_in[0];
  const float* W_ih = (const float*)d_in[1];
  const float* W_hh = (const float*)d_in[2];
  const float* b_ih = (const float*)d_in[3];
  const float* b_hh = (const float*)d_in[4];
  const float* W_proj = (const float*)d_in[5];
  float* out = (float*)d_out;

  int xstride = (in_sizes[0] > Bsz * SQL) ? 2 : 1;

  // workspace layout (~89 MB)
  u16* whh_hi = (u16*)d_ws;
  u16* whh_lo = whh_hi + (long)G4H * Hdim;
  float* wihT2 = (float*)(whh_lo + (long)G4H * Hdim);
  float* bias2 = wihT2 + (long)Vsz * G4H;
  float* ic = bias2 + G4H;
  float* hf = ic + (long)Bsz * G4H;
  float* c = hf + (long)Bsz * Hdim;
  float* outq = c + (long)Bsz * Hdim;
  float* lg = outq + (long)Bsz * Hdim;
  u16* hA_hi = (u16*)(lg + Bsz * Vsz);
  u16* hA_lo = hA_hi + (long)Bsz * Hdim;
  u16* hB_hi = hA_lo + (long)Bsz * Hdim;
  u16* hB_lo = hB_hi + (long)Bsz * Hdim;

  k_split2<<<4096, 256, 0, stream>>>(W_hh, whh_hi, whh_lo);
  k_prep<<<3040, 256, 0, stream>>>(W_ih, b_ih, b_hh, wihT2, bias2, hf, c, hA_hi, hA_lo);

  u16* ih[2] = {hA_hi, hB_hi};
  u16* il[2] = {hA_lo, hB_lo};
  int pp = 0;
  dim3 gg(2, 128);

  // Phase 1: question (one-hot gather input fused into epilogue)
  for (int t = 0; t < SQL; ++t) {
    k_step<<<gg, 256, 0, stream>>>(ih[pp], il[pp], whh_hi, whh_lo, bias2, wihT2,
                                   nullptr, x, t, xstride, 1, c, hf, ih[pp ^ 1],
                                   il[pp ^ 1]);
    pp ^= 1;
  }
  hipMemcpyAsync(outq, hf, (long)Bsz * Hdim * sizeof(float),
                 hipMemcpyDeviceToDevice, stream);

  // Phase 2: thinking (zero input)
  for (int t = 0; t < TSTEPS; ++t) {
    k_step<<<gg, 256, 0, stream>>>(ih[pp], il[pp], whh_hi, whh_lo, bias2, wihT2,
                                   nullptr, nullptr, 0, 1, 0, c, hf, ih[pp ^ 1],
                                   il[pp ^ 1]);
    pp ^= 1;
  }

  // Phase 3: autoregressive answer (logits fed back)
  for (int s = 0; s < ASTEPS; ++s) {
    const float* src = (s == 0) ? outq : hf;
    k_logits<<<Bsz, 256, 0, stream>>>(src, W_proj, lg, out + (long)s * Bsz * Vsz);
    k_ic<<<dim3(32, 32), 256, 0, stream>>>(lg, wihT2, ic);
    k_step<<<gg, 256, 0, stream>>>(ih[pp], il[pp], whh_hi, whh_lo, bias2, wihT2,
                                   ic, nullptr, 0, 1, 2, c, hf, ih[pp ^ 1],
                                   il[pp ^ 1]);
    pp ^= 1;
  }
}

// Round 3
// 14320.949 us; speedup vs baseline: 1.2285x; 1.2285x over previous
//
#include <hip/hip_runtime.h>

// SimpleLSTM: V=95, H=2048, B=256, SQ=162, 15 think + 29 answer steps.
// Round 2: counted-vmcnt 4-stage pipeline (T3+T4), 8 waves, raw s_barrier,
// setprio around MFMA (T5), XCD-aware block swizzle (T1).
// Numerics: 3-term split-bf16 MFMA (hi*hi + hi*lo + lo*hi), fp32 accum.

#define Hdim 2048
#define G4H  8192
#define Bsz  256
#define Vsz  95
#define SQL  162
#define TSTEPS 15
#define ASTEPS 29

typedef unsigned short u16;
typedef __attribute__((ext_vector_type(8))) short bf16x8;
typedef __attribute__((ext_vector_type(4))) float f32x4;

__device__ __forceinline__ u16 f2bf(float x) {
  unsigned u = __float_as_uint(x);
  return (u16)((u + 0x7fffu + ((u >> 16) & 1u)) >> 16);
}
__device__ __forceinline__ float bf2f(u16 v) {
  return __uint_as_float(((unsigned)v) << 16);
}
__device__ __forceinline__ void splitbf(float x, u16& hi, u16& lo) {
  hi = f2bf(x);
  lo = f2bf(x - bf2f(hi));
}
__device__ __forceinline__ float sigm(float x) { return 1.0f / (1.0f + expf(-x)); }

__device__ __forceinline__ void gll16(const u16* g, u16* l) {
  __builtin_amdgcn_global_load_lds(
      (const __attribute__((address_space(1))) void*)g,
      (__attribute__((address_space(3))) void*)l, 16, 0, 0);
}

#define VMWAIT(n) asm volatile("s_waitcnt vmcnt(" #n ")" ::: "memory")

// ---------------- init: gate-interleaved split of W_hh ----------------
__global__ void k_split2(const float* __restrict__ w, u16* __restrict__ whi,
                         u16* __restrict__ wlo) {
  for (long i = blockIdx.x * blockDim.x + threadIdx.x; i < (long)G4H * Hdim;
       i += (long)gridDim.x * blockDim.x) {
    int n = (int)(i >> 11), k = (int)(i & 2047);
    long r = (long)((n & 3) * Hdim + (n >> 2));
    u16 a, b;
    splitbf(w[r * Hdim + k], a, b);
    whi[i] = a;
    wlo[i] = b;
  }
}

__global__ void k_prep(const float* __restrict__ W_ih, const float* __restrict__ b_ih,
                       const float* __restrict__ b_hh, float* __restrict__ wihT2,
                       float* __restrict__ bias2, float* __restrict__ h,
                       float* __restrict__ c, u16* __restrict__ h_hi,
                       u16* __restrict__ h_lo) {
  int i = blockIdx.x * 256 + threadIdx.x;
  if (i < Vsz * G4H) {
    int v = i / G4H, n = i % G4H;
    int r = (n & 3) * Hdim + (n >> 2);
    wihT2[i] = W_ih[(long)r * Vsz + v];
  }
  if (i < G4H) {
    int r = (i & 3) * Hdim + (i >> 2);
    bias2[i] = b_ih[r] + b_hh[r];
  }
  if (i < Bsz * Hdim) {
    h[i] = 0.f;
    c[i] = 0.f;
    h_hi[i] = 0;
    h_lo[i] = 0;
  }
}

// ---------------- fused step: g = h@W_hh.T (+input) -> gates -> h,c ----------
// Tile BM=128 BN=64 BK=32, logical grid (2,128), 8 waves (4Mx2N, wave 32x32).
// LDS: 4-stage x 24KB [Ah 8K | Al 8K | Bh 4K | Bl 4K], counted-vmcnt pipeline.
__global__ __launch_bounds__(512) void k_step(
    const u16* __restrict__ a_hi, const u16* __restrict__ a_lo,
    const u16* __restrict__ b_hi, const u16* __restrict__ b_lo,
    const float* __restrict__ bias2, const float* __restrict__ wihT2,
    const float* __restrict__ ic, const int* __restrict__ x, int tstep,
    int xstride, int mode, float* __restrict__ c, float* __restrict__ hf,
    u16* __restrict__ o_hi, u16* __restrict__ o_lo) {
  __shared__ __align__(16) u16 SM[49152];  // 96 KB = 4 stages x 24 KB

  const int tid = threadIdx.x;
  const int wave = tid >> 6, lane = tid & 63;

  // XCD-aware swizzle (T1): hw linear id -> each XCD owns 16 consecutive
  // col-tiles (both M-halves co-located). 256 blocks, %8==0, bijective.
  const int lin = blockIdx.x + blockIdx.y * 2;
  const int lin2 = (lin & 7) * 32 + (lin >> 3);
  const int row0 = (lin2 & 1) * 128;
  const int col0 = (lin2 >> 1) * 64;

  const int wr = wave >> 1, wc = wave & 1;
  const int lr = lane & 15, lc = lane >> 4;

  // --- staging: 3 global_load_lds per wave per K-round, chunk cc = wave*3+j
  const u16* gsrc[3];
  u16* ldst[3];
#pragma unroll
  for (int j = 0; j < 3; ++j) {
    int cc = wave * 3 + j;
    const u16* base;
    long rg;
    if (cc < 8)       { base = a_hi; rg = row0 + cc * 16; }
    else if (cc < 16) { base = a_lo; rg = row0 + (cc - 8) * 16; }
    else if (cc < 20) { base = b_hi; rg = col0 + (cc - 16) * 16; }
    else              { base = b_lo; rg = col0 + (cc - 20) * 16; }
    // per-lane row += lane>>2 ; source k-slot pre-swizzled (G21 both-sides)
    gsrc[j] = base + (rg + (lane >> 2)) * (long)Hdim +
              (((lane & 3) ^ ((lane >> 2) & 3)) * 8);
    ldst[j] = SM + cc * 512;  // linear LDS dest, 1KB per instr
  }

  // --- read byte-offsets within a stage (swizzled k-slot)
  const int sl = (lc ^ (lr & 3)) * 16;
  int aoff[2], boff[2];
#pragma unroll
  for (int mf = 0; mf < 2; ++mf) aoff[mf] = (wr * 32 + mf * 16 + lr) * 64 + sl;
#pragma unroll
  for (int nf = 0; nf < 2; ++nf) boff[nf] = 16384 + (wc * 32 + nf * 16 + lr) * 64 + sl;

  f32x4 acc[2][2] = {};
  const char* smb = (const char*)SM;

#define STAGE(s)                                                      \
  {                                                                   \
    const int _o = ((s) & 3) * 12288;                                 \
    _Pragma("unroll") for (int j = 0; j < 3; ++j)                     \
        gll16(gsrc[j] + (s) * 32, ldst[j] + _o);                      \
  }

#define COMPUTE(kb)                                                             \
  {                                                                             \
    const char* sb = smb + ((kb) & 3) * 24576;                                  \
    bf16x8 ah0 = *(const bf16x8*)(sb + aoff[0]);                                \
    bf16x8 ah1 = *(const bf16x8*)(sb + aoff[1]);                                \
    bf16x8 al0 = *(const bf16x8*)(sb + 8192 + aoff[0]);                         \
    bf16x8 al1 = *(const bf16x8*)(sb + 8192 + aoff[1]);                         \
    bf16x8 bh0 = *(const bf16x8*)(sb + boff[0]);                                \
    bf16x8 bh1 = *(const bf16x8*)(sb + boff[1]);                                \
    bf16x8 bl0 = *(const bf16x8*)(sb + 4096 + boff[0]);                         \
    bf16x8 bl1 = *(const bf16x8*)(sb + 4096 + boff[1]);                         \
    __builtin_amdgcn_s_setprio(1);                                              \
    acc[0][0] = __builtin_amdgcn_mfma_f32_16x16x32_bf16(ah0, bh0, acc[0][0], 0, 0, 0); \
    acc[0][1] = __builtin_amdgcn_mfma_f32_16x16x32_bf16(ah0, bh1, acc[0][1], 0, 0, 0); \
    acc[1][0] = __builtin_amdgcn_mfma_f32_16x16x32_bf16(ah1, bh0, acc[1][0], 0, 0, 0); \
    acc[1][1] = __builtin_amdgcn_mfma_f32_16x16x32_bf16(ah1, bh1, acc[1][1], 0, 0, 0); \
    acc[0][0] = __builtin_amdgcn_mfma_f32_16x16x32_bf16(ah0, bl0, acc[0][0], 0, 0, 0); \
    acc[0][1] = __builtin_amdgcn_mfma_f32_16x16x32_bf16(ah0, bl1, acc[0][1], 0, 0, 0); \
    acc[1][0] = __builtin_amdgcn_mfma_f32_16x16x32_bf16(ah1, bl0, acc[1][0], 0, 0, 0); \
    acc[1][1] = __builtin_amdgcn_mfma_f32_16x16x32_bf16(ah1, bl1, acc[1][1], 0, 0, 0); \
    acc[0][0] = __builtin_amdgcn_mfma_f32_16x16x32_bf16(al0, bh0, acc[0][0], 0, 0, 0); \
    acc[0][1] = __builtin_amdgcn_mfma_f32_16x16x32_bf16(al0, bh1, acc[0][1], 0, 0, 0); \
    acc[1][0] = __builtin_amdgcn_mfma_f32_16x16x32_bf16(al1, bh0, acc[1][0], 0, 0, 0); \
    acc[1][1] = __builtin_amdgcn_mfma_f32_16x16x32_bf16(al1, bh1, acc[1][1], 0, 0, 0); \
    __builtin_amdgcn_s_setprio(0);                                              \
  }

  // prologue: 3 stages in flight (9 loads/wave)
  STAGE(0); STAGE(1); STAGE(2);

  // main loop: wait own round-kb loads (keep 6 outstanding), barrier,
  // issue round kb+3, compute round kb. vmcnt never drained to 0.
  for (int kb = 0; kb < 62; ++kb) {
    VMWAIT(6);
    __builtin_amdgcn_s_barrier();
    if (kb < 61) STAGE(kb + 3);
    COMPUTE(kb);
  }
  VMWAIT(3);
  __builtin_amdgcn_s_barrier();
  COMPUTE(62);
  VMWAIT(0);
  __builtin_amdgcn_s_barrier();
  COMPUTE(63);

  // --- epilogue: g-tile via LDS (padded stride 68), fused gates
  __syncthreads();
  float* gt = (float*)SM;
#pragma unroll
  for (int mf = 0; mf < 2; ++mf)
#pragma unroll
    for (int nf = 0; nf < 2; ++nf) {
      int col = wc * 32 + nf * 16 + lr;
#pragma unroll
      for (int i = 0; i < 4; ++i) {
        int row = wr * 32 + mf * 16 + lc * 4 + i;
        gt[row * 68 + col] = acc[mf][nf][i];
      }
    }
  __syncthreads();

  const int h16 = tid & 15;    // local hh (16 per block)
  const int bl32 = tid >> 4;   // 0..31 row group
  const int hh_g = (col0 >> 2) + h16;
  const float bi = bias2[col0 + 4 * h16 + 0];
  const float bf_ = bias2[col0 + 4 * h16 + 1];
  const float bg_ = bias2[col0 + 4 * h16 + 2];
  const float bo = bias2[col0 + 4 * h16 + 3];
#pragma unroll
  for (int p = 0; p < 4; ++p) {
    int brow = p * 32 + bl32;
    int bg = row0 + brow;
    const float* gr = &gt[brow * 68 + 4 * h16];
    float xi = gr[0] + bi, xf = gr[1] + bf_, xg = gr[2] + bg_, xo = gr[3] + bo;
    if (mode == 1) {
      int tok = x[(bg * SQL + tstep) * xstride];
      const float* wv = wihT2 + (long)tok * G4H + col0 + 4 * h16;
      xi += wv[0]; xf += wv[1]; xg += wv[2]; xo += wv[3];
    } else if (mode == 2) {
      const float* iv = ic + (long)bg * G4H + col0 + 4 * h16;
      xi += iv[0]; xf += iv[1]; xg += iv[2]; xo += iv[3];
    }
    long ci = (long)bg * Hdim + hh_g;
    float cn = sigm(xf) * c[ci] + sigm(xi) * tanhf(xg);
    float hn = sigm(xo) * tanhf(cn);
    c[ci] = cn;
    hf[ci] = hn;
    u16 h_, l_;
    splitbf(hn, h_, l_);
    o_hi[ci] = h_;
    o_lo[ci] = l_;
  }
#undef STAGE
#undef COMPUTE
}

// ---------------- logits = src @ W_proj.T (fp32) ----------------
__global__ __launch_bounds__(256) void k_logits(const float* __restrict__ src,
                                                const float* __restrict__ Wp,
                                                float* __restrict__ lg,
                                                float* __restrict__ outp) {
  __shared__ float hl[Hdim];
  int b = blockIdx.x, tid = threadIdx.x;
  for (int k = tid; k < Hdim; k += 256) hl[k] = src[(long)b * Hdim + k];
  __syncthreads();
  int wv = tid >> 6, ln = tid & 63;
  for (int v = wv; v < Vsz; v += 4) {
    const float* wrow = Wp + (long)v * Hdim;
    float s = 0.f;
    for (int k = ln; k < Hdim; k += 64) s += wrow[k] * hl[k];
#pragma unroll
    for (int off = 32; off; off >>= 1) s += __shfl_down(s, off);
    if (ln == 0) {
      lg[b * Vsz + v] = s;
      outp[b * Vsz + v] = s;
    }
  }
}

// ---------------- ic = logits @ W_ih.T (K=95), gate-interleaved out --------
__global__ __launch_bounds__(256) void k_ic(const float* __restrict__ lg,
                                            const float* __restrict__ wihT2,
                                            float* __restrict__ ic) {
  __shared__ float ll[8 * Vsz];
  int jg = blockIdx.x, bgp = blockIdx.y, tid = threadIdx.x;
  int j = jg * 256 + tid;
  for (int i = tid; i < 8 * Vsz; i += 256) ll[i] = lg[bgp * 8 * Vsz + i];
  __syncthreads();
  float a[8] = {0, 0, 0, 0, 0, 0, 0, 0};
  for (int v = 0; v < Vsz; ++v) {
    float w = wihT2[(long)v * G4H + j];
#pragma unroll
    for (int bb = 0; bb < 8; ++bb) a[bb] += ll[bb * Vsz + v] * w;
  }
#pragma unroll
  for (int bb = 0; bb < 8; ++bb) ic[(long)(bgp * 8 + bb) * G4H + j] = a[bb];
}

// ---------------- host ----------------
extern "C" void kernel_launch(void* const* d_in, const int* in_sizes, int n_in,
                              void* d_out, int out_size, void* d_ws, size_t ws_size,
                              hipStream_t stream) {
  const int* x = (const int*)d_in[0];
  const float* W_ih = (const float*)d_in[1];
  const float* W_hh = (const float*)d_in[2];
  const float* b_ih = (const float*)d_in[3];
  const float* b_hh = (const float*)d_in[4];
  const float* W_proj = (const float*)d_in[5];
  float* out = (float*)d_out;

  int xstride = (in_sizes[0] > Bsz * SQL) ? 2 : 1;

  // workspace layout (~89 MB)
  u16* whh_hi = (u16*)d_ws;
  u16* whh_lo = whh_hi + (long)G4H * Hdim;
  float* wihT2 = (float*)(whh_lo + (long)G4H * Hdim);
  float* bias2 = wihT2 + (long)Vsz * G4H;
  float* ic = bias2 + G4H;
  float* hf = ic + (long)Bsz * G4H;
  float* c = hf + (long)Bsz * Hdim;
  float* outq = c + (long)Bsz * Hdim;
  float* lg = outq + (long)Bsz * Hdim;
  u16* hA_hi = (u16*)(lg + Bsz * Vsz);
  u16* hA_lo = hA_hi + (long)Bsz * Hdim;
  u16* hB_hi = hA_lo + (long)Bsz * Hdim;
  u16* hB_lo = hB_hi + (long)Bsz * Hdim;

  k_split2<<<4096, 256, 0, stream>>>(W_hh, whh_hi, whh_lo);
  k_prep<<<3040, 256, 0, stream>>>(W_ih, b_ih, b_hh, wihT2, bias2, hf, c, hA_hi, hA_lo);

  u16* ih[2] = {hA_hi, hB_hi};
  u16* il[2] = {hA_lo, hB_lo};
  int pp = 0;
  dim3 gg(2, 128);

  // Phase 1: question (one-hot gather fused into epilogue)
  for (int t = 0; t < SQL; ++t) {
    k_step<<<gg, 512, 0, stream>>>(ih[pp], il[pp], whh_hi, whh_lo, bias2, wihT2,
                                   nullptr, x, t, xstride, 1, c, hf, ih[pp ^ 1],
                                   il[pp ^ 1]);
    pp ^= 1;
  }
  hipMemcpyAsync(outq, hf, (long)Bsz * Hdim * sizeof(float),
                 hipMemcpyDeviceToDevice, stream);

  // Phase 2: thinking (zero input)
  for (int t = 0; t < TSTEPS; ++t) {
    k_step<<<gg, 512, 0, stream>>>(ih[pp], il[pp], whh_hi, whh_lo, bias2, wihT2,
                                   nullptr, nullptr, 0, 1, 0, c, hf, ih[pp ^ 1],
                                   il[pp ^ 1]);
    pp ^= 1;
  }

  // Phase 3: autoregressive answer (logits fed back)
  for (int s = 0; s < ASTEPS; ++s) {
    const float* src = (s == 0) ? outq : hf;
    k_logits<<<Bsz, 256, 0, stream>>>(src, W_proj, lg, out + (long)s * Bsz * Vsz);
    k_ic<<<dim3(32, 32), 256, 0, stream>>>(lg, wihT2, ic);
    k_step<<<gg, 512, 0, stream>>>(ih[pp], il[pp], whh_hi, whh_lo, bias2, wihT2,
                                   ic, nullptr, 0, 1, 2, c, hf, ih[pp ^ 1],
                                   il[pp ^ 1]);
    pp ^= 1;
  }
}